// Round 3
// baseline (427.110 us; speedup 1.0000x reference)
//
#include <hip/hip_runtime.h>
#include <hip/hip_bf16.h>

// Problem constants (fixed by the reference)
#define NROW 2048
#define HDIM 1024
#define VOC  50304
#define KCL  16
#define CDIM 3144   // VOC / KCL

// Tail-GEMM tiling
#define MT 128      // rows per in-block chunk
#define NTC 64      // col tile
#define NCT ((CDIM + NTC - 1) / NTC)   // 50 col tiles
#define CAP 256     // per-cluster row capacity (Binomial(2048,1/16): mean 128, sd ~11)

// Workspace layout in 4-byte units (~8.6 MB total)
#define WS_SUMEXP 0            // float[2048]   (zeroed each call)
#define WS_COUNTS 2048         // int[16]       (zeroed each call)
#define WS_PART   2064         // float[2048]
#define WS_ZTGT   4112         // float[2048]
#define WS_TCOL   6160         // int[2048]
#define WS_ROWS   8208         // int[16*2048]
#define WS_XG     40976        // bf16 xgT[16][128][256][8] = 8.4 MB (16B aligned)

typedef __attribute__((ext_vector_type(8))) short short8;
typedef __attribute__((ext_vector_type(4))) float f32x4;

__device__ __forceinline__ ushort2 f2bf2(float a, float b) {
    union { __hip_bfloat162 h; ushort2 u; } cv;
    cv.h = __float22bfloat162_rn(float2{a, b});
    return cv.u;
}

// ---------------------------------------------------------------------------
// Kernel 1: bucket rows by cluster, record target within-cluster column
// ---------------------------------------------------------------------------
__global__ void scatter_kernel(const int* __restrict__ y,
                               const int* __restrict__ y_pos,
                               const int* __restrict__ tip,   // token_in_pos_id [K][V]
                               int* ws_i) {
    int n = blockIdx.x * 256 + threadIdx.x;
    if (n >= NROW) return;
    int kn = y_pos[n];
    int slot = atomicAdd(&ws_i[WS_COUNTS + kn], 1);
    ws_i[WS_ROWS + kn * NROW + slot] = n;
    ws_i[WS_TCOL + n] = tip[kn * VOC + y[n]];   // within-cluster target col
}

// ---------------------------------------------------------------------------
// Kernel 2 (prep): block = 4 waves = 4 slots of one cluster.
//  - gathers x[row] -> bf16, TRANSPOSED store xgT[k][h8][slot][8] via LDS so
//    both the global read and the global write are coalesced
//  - fused cluster-logsumexp part (wave-local, register shuffles only)
// ---------------------------------------------------------------------------
__global__ void prep_kernel(const float* __restrict__ x,
                            const float* __restrict__ cw,   // [H][K]
                            const int* __restrict__ ws_i, float* ws_f) {
    __shared__ __align__(16) short rb[4][128][8];   // 8KB: [slot_local][h8][8]

    const int wv   = threadIdx.x >> 6;
    const int lane = threadIdx.x & 63;
    const int b = blockIdx.x;            // 1024 blocks: 64 per cluster
    const int k = b >> 6;
    const int slot0 = (b & 63) * 4;
    const int slot  = slot0 + wv;
    const int Mk = ws_i[WS_COUNTS + k];

    float4 v[4];
    if (slot < Mk) {
        const int n = ws_i[WS_ROWS + k * NROW + slot];
        const float4* xr = (const float4*)(x + (size_t)n * HDIM);
#pragma unroll
        for (int q = 0; q < 4; q++) v[q] = xr[q * 64 + lane];  // h = q*256 + lane*4 ..+4
    } else {
#pragma unroll
        for (int q = 0; q < 4; q++) v[q] = float4{0.f, 0.f, 0.f, 0.f};
    }
    // cvt + LDS stage: granule h8 = q*32 + lane/2, half = lane&1
#pragma unroll
    for (int q = 0; q < 4; q++) {
        union { ushort2 u2[2]; uint2 u; } t;
        t.u2[0] = f2bf2(v[q].x, v[q].y);
        t.u2[1] = f2bf2(v[q].z, v[q].w);
        *(uint2*)&rb[wv][q * 32 + (lane >> 1)][(lane & 1) * 4] = t.u;
    }
    // cluster logits (wave-uniform branch; register-only reduce)
    if (slot < Mk) {
        float acc[KCL];
#pragma unroll
        for (int kk = 0; kk < KCL; kk++) acc[kk] = 0.f;
#pragma unroll
        for (int q = 0; q < 4; q++) {
            const float* vf = (const float*)&v[q];
#pragma unroll
            for (int e = 0; e < 4; e++) {
                const int h = q * 256 + lane * 4 + e;
                const float xv = vf[e];
                const float4* cwr = (const float4*)(cw + (size_t)h * KCL);
#pragma unroll
                for (int qq = 0; qq < 4; qq++) {
                    float4 wgt = cwr[qq];
                    acc[qq * 4 + 0] += xv * wgt.x;
                    acc[qq * 4 + 1] += xv * wgt.y;
                    acc[qq * 4 + 2] += xv * wgt.z;
                    acc[qq * 4 + 3] += xv * wgt.w;
                }
            }
        }
#pragma unroll
        for (int off = 32; off >= 1; off >>= 1) {
#pragma unroll
            for (int kk = 0; kk < KCL; kk++) acc[kk] += __shfl_down(acc[kk], off);
        }
        if (lane == 0) {
            const int n = ws_i[WS_ROWS + k * NROW + slot];
            float m = acc[0];
#pragma unroll
            for (int kk = 1; kk < KCL; kk++) m = fmaxf(m, acc[kk]);
            float s = 0.f;
#pragma unroll
            for (int kk = 0; kk < KCL; kk++) s += __expf(acc[kk] - m);
            ws_f[WS_PART + n] = (m + __logf(s)) - acc[k];
        }
    }
    __syncthreads();
    // write out: thread -> (h8 = tid>>1, slots sp..sp+1), 32B contiguous
    {
        const int h8 = threadIdx.x >> 1;
        const int sp = (threadIdx.x & 1) * 2;
        short* o = (short*)(ws_i + WS_XG)
                 + ((size_t)k * (128 * 256) + (size_t)h8 * 256 + slot0 + sp) * 8;
        *(short8*)(o)     = *(const short8*)&rb[sp][h8][0];
        *(short8*)(o + 8) = *(const short8*)&rb[sp + 1][h8][0];
    }
}

// ---------------------------------------------------------------------------
// Kernel 3: tail GEMM, BARRIER-FREE / LDS-FREE K-loop.
// Grid = (50 col tiles, 16 clusters); block = 4 waves (2 row-halves x 2
// col-halves of a 128x64 tile); in-block loop over 128-row chunks so each
// B element is read from HBM exactly once (206 MB total = the roofline).
// A fragments load directly from the L2/L3-resident xgT (fragment-ordered);
// B fragments load directly from logits as 8 fp32 scalars per frag (64B
// coalesced per 16-lane group) + cvt. Manual 2-buffer software pipeline;
// compiler emits counted vmcnt waits (no barrier -> no vmcnt(0) drain).
// ---------------------------------------------------------------------------
__launch_bounds__(256, 3)
__global__ void tail_kernel(const float* __restrict__ logits,
                            const int* ws_i, float* ws_f) {
    __shared__ int   lrow[MT];
    __shared__ int   ltcol[MT];
    __shared__ float rowsum[MT];

    const int k  = blockIdx.y;
    const int ct = blockIdx.x;
    int Mk = ws_i[WS_COUNTS + k];
    if (Mk > CAP) Mk = CAP;

    const int tid = threadIdx.x;
    const int w  = tid >> 6, l = tid & 63;
    const int wr = (w & 1) * 64;        // wave row-half (within 128-row chunk)
    const int wc = (w >> 1) * 32;       // wave col-half (within 64-col tile)
    const int quad = l >> 4, lm = l & 15;

    // B bases: lane covers col (clamped; masked in epilogue), k-rows quad*8+j
    const float* bBase0;
    const float* bBase1;
    {
        int c0 = ct * NTC + wc + lm;       if (c0 >= CDIM) c0 = CDIM - 1;
        int c1 = ct * NTC + wc + 16 + lm;  if (c1 >= CDIM) c1 = CDIM - 1;
        const float* base = logits + (size_t)(quad * 8) * VOC + (size_t)k * CDIM;
        bBase0 = base + c0;
        bBase1 = base + c1;
    }
    const short* xgT = (const short*)(ws_i + WS_XG);

    for (int r0 = 0; r0 < Mk; r0 += MT) {
        __syncthreads();   // protect lrow/rowsum reuse across chunks
        if (tid < MT) {
            int r = r0 + tid;
            int rid = (r < Mk) ? ws_i[WS_ROWS + k * NROW + r] : -1;
            lrow[tid]  = rid;
            ltcol[tid] = (rid >= 0) ? ws_i[WS_TCOL + rid] : -1;
            rowsum[tid] = 0.f;
        }
        __syncthreads();

        // A base: granule (h8 = t*4 + quad, slot = r0 + wr + mi*16 + lm)
        const short* aBase = xgT
            + (((size_t)k * 128 + quad) * 256 + (size_t)(r0 + wr + lm)) * 8;

        f32x4 acc[4][2];
#pragma unroll
        for (int mi = 0; mi < 4; mi++)
#pragma unroll
            for (int ni = 0; ni < 2; ni++) acc[mi][ni] = (f32x4)(0.f);

        float  bv0[2][8], bv1[2][8];
        short8 af0[4],    af1[4];

        auto LOADA = [&](int t, short8* af) {
#pragma unroll
            for (int mi = 0; mi < 4; mi++)
                af[mi] = *(const short8*)(aBase + (size_t)t * 8192 + mi * 128);
        };
        auto LOADB = [&](int t, float bv[2][8]) {
            const float* p0 = bBase0 + (size_t)t * 32 * VOC;
            const float* p1 = bBase1 + (size_t)t * 32 * VOC;
#pragma unroll
            for (int j = 0; j < 8; j++) bv[0][j] = p0[(size_t)j * VOC];
#pragma unroll
            for (int j = 0; j < 8; j++) bv[1][j] = p1[(size_t)j * VOC];
        };
        auto COMPUTE = [&](float bv[2][8], short8* af) {
            short8 bf[2];
#pragma unroll
            for (int ni = 0; ni < 2; ni++) {
                union { ushort2 u2[4]; short8 s8; } u;
#pragma unroll
                for (int jj = 0; jj < 4; jj++)
                    u.u2[jj] = f2bf2(bv[ni][2 * jj], bv[ni][2 * jj + 1]);
                bf[ni] = u.s8;
            }
#pragma unroll
            for (int mi = 0; mi < 4; mi++)
#pragma unroll
                for (int ni = 0; ni < 2; ni++)
                    acc[mi][ni] = __builtin_amdgcn_mfma_f32_16x16x32_bf16(
                        af[mi], bf[ni], acc[mi][ni], 0, 0, 0);
        };

        // ---- software-pipelined K-loop, no barriers ----
        LOADB(0, bv0);
        LOADA(0, af0);
        for (int t = 0; t < HDIM / 32; t += 2) {
            LOADB(t + 1, bv1);              // issue next-step loads first
            LOADA(t + 1, af1);
            COMPUTE(bv0, af0);              // waits (counted) on bv0/af0 only
            if (t + 2 < HDIM / 32) {
                LOADB(t + 2, bv0);
                LOADA(t + 2, af0);
            }
            COMPUTE(bv1, af1);
        }

        // ---- epilogue: per-row sum(exp) + target logit ----
        // C/D layout: col = lane&15, row = (lane>>4)*4 + reg  [m89-verified]
#pragma unroll
        for (int mi = 0; mi < 4; mi++) {
#pragma unroll
            for (int r = 0; r < 4; r++) {
                int row_local = wr + mi * 16 + quad * 4 + r;
                int rid = lrow[row_local];
                int tc  = ltcol[row_local];
                float s = 0.f;
#pragma unroll
                for (int ni = 0; ni < 2; ni++) {
                    int cl = ct * NTC + wc + ni * 16 + lm;
                    float z = acc[mi][ni][r];
                    if (rid >= 0 && cl < CDIM) {
                        s += __expf(z);
                        if (cl == tc) ws_f[WS_ZTGT + rid] = z;
                    }
                }
                s += __shfl_xor(s, 1);
                s += __shfl_xor(s, 2);
                s += __shfl_xor(s, 4);
                s += __shfl_xor(s, 8);
                if (lm == 0 && rid >= 0) atomicAdd(&rowsum[row_local], s);
            }
        }
        __syncthreads();
        if (tid < MT) {
            int rid = lrow[tid];
            if (rid >= 0) atomicAdd(&ws_f[WS_SUMEXP + rid], rowsum[tid]);
        }
    }
}

// ---------------------------------------------------------------------------
// Kernel 4: nll[n] = part[n] + log(sum_exp_tail[n]) - z_target[n]
// ---------------------------------------------------------------------------
__global__ void finalize_kernel(const float* ws_f, float* __restrict__ out) {
    int n = blockIdx.x * 256 + threadIdx.x;
    if (n >= NROW) return;
    out[n] = ws_f[WS_PART + n] + __logf(ws_f[WS_SUMEXP + n]) - ws_f[WS_ZTGT + n];
}

// ---------------------------------------------------------------------------
extern "C" void kernel_launch(void* const* d_in, const int* in_sizes, int n_in,
                              void* d_out, int out_size, void* d_ws, size_t ws_size,
                              hipStream_t stream) {
    const float* x      = (const float*)d_in[0];
    const int*   y      = (const int*)d_in[1];
    const int*   y_pos  = (const int*)d_in[2];
    // d_in[3] (pos2token) is the identity partition by construction; unused.
    const int*   tip    = (const int*)d_in[4];
    const float* cw     = (const float*)d_in[5];
    const float* logits = (const float*)d_in[6];
    float* out  = (float*)d_out;
    float* ws_f = (float*)d_ws;
    int*   ws_i = (int*)d_ws;

    // zero sumexp[2048] + counts[16] (contiguous at ws start)
    hipMemsetAsync(d_ws, 0, (size_t)(NROW + KCL) * 4, stream);

    scatter_kernel<<<NROW / 256, 256, 0, stream>>>(y, y_pos, tip, ws_i);
    // 16 clusters x 64 blocks (4 slots each): gather+transpose+cluster lse
    prep_kernel<<<KCL * CAP / 4, 256, 0, stream>>>(x, cw, ws_i, ws_f);

    // 50 col tiles x 16 clusters; row chunks looped inside the block so
    // logits is read from HBM exactly once.
    dim3 grid(NCT, KCL);
    tail_kernel<<<grid, 256, 0, stream>>>(logits, ws_i, ws_f);

    finalize_kernel<<<NROW / 256, 256, 0, stream>>>(ws_f, out);
}

// Round 4
// 420.336 us; speedup vs baseline: 1.0161x; 1.0161x over previous
//
#include <hip/hip_runtime.h>
#include <hip/hip_bf16.h>

// Problem constants (fixed by the reference)
#define NROW 2048
#define HDIM 1024
#define VOC  50304
#define KCL  16
#define CDIM 3144   // VOC / KCL

// Tail-GEMM tiling
#define MT 192      // rows per block (Mk ~ 128+-11 -> one chunk; z=2 guards 6-sigma)
#define NTC 32      // col tile
#define NCT ((CDIM + NTC - 1) / NTC)   // 99 col tiles
#define CAP 256     // per-cluster row capacity in xgT

// Workspace layout in 4-byte units (~8.6 MB total)
#define WS_SUMEXP 0            // float[2048]   (zeroed each call)
#define WS_COUNTS 2048         // int[16]       (zeroed each call)
#define WS_PART   2064         // float[2048]
#define WS_ZTGT   4112         // float[2048]
#define WS_TCOL   6160         // int[2048]
#define WS_ROWS   8208         // int[16*2048]
#define WS_XG     40976        // bf16 xgT[16][128][256][8] = 8.4 MB (16B aligned)

typedef __attribute__((ext_vector_type(8))) short short8;
typedef __attribute__((ext_vector_type(4))) float f32x4;

__device__ __forceinline__ ushort2 f2bf2(float a, float b) {
    union { __hip_bfloat162 h; ushort2 u; } cv;
    cv.h = __float22bfloat162_rn(float2{a, b});
    return cv.u;
}

// ---------------------------------------------------------------------------
// Kernel 1: bucket rows by cluster, record target within-cluster column
// ---------------------------------------------------------------------------
__global__ void scatter_kernel(const int* __restrict__ y,
                               const int* __restrict__ y_pos,
                               const int* __restrict__ tip,   // token_in_pos_id [K][V]
                               int* ws_i) {
    int n = blockIdx.x * 256 + threadIdx.x;
    if (n >= NROW) return;
    int kn = y_pos[n];
    int slot = atomicAdd(&ws_i[WS_COUNTS + kn], 1);
    ws_i[WS_ROWS + kn * NROW + slot] = n;
    ws_i[WS_TCOL + n] = tip[kn * VOC + y[n]];   // within-cluster target col
}

// ---------------------------------------------------------------------------
// Kernel 2 (prep): block = 4 waves = 4 slots of one cluster.
//  - gathers x[row] -> bf16, TRANSPOSED store xgT[k][h8][slot][8] via LDS so
//    both the global read and the global write are coalesced
//  - fused cluster-logsumexp part (wave-local, register shuffles only)
// ---------------------------------------------------------------------------
__global__ void prep_kernel(const float* __restrict__ x,
                            const float* __restrict__ cw,   // [H][K]
                            const int* __restrict__ ws_i, float* ws_f) {
    __shared__ __align__(16) short rb[4][128][8];   // 8KB: [slot_local][h8][8]

    const int wv   = threadIdx.x >> 6;
    const int lane = threadIdx.x & 63;
    const int b = blockIdx.x;            // 1024 blocks: 64 per cluster
    const int k = b >> 6;
    const int slot0 = (b & 63) * 4;
    const int slot  = slot0 + wv;
    const int Mk = ws_i[WS_COUNTS + k];

    float4 v[4];
    if (slot < Mk) {
        const int n = ws_i[WS_ROWS + k * NROW + slot];
        const float4* xr = (const float4*)(x + (size_t)n * HDIM);
#pragma unroll
        for (int q = 0; q < 4; q++) v[q] = xr[q * 64 + lane];  // h = q*256 + lane*4 ..+4
    } else {
#pragma unroll
        for (int q = 0; q < 4; q++) v[q] = float4{0.f, 0.f, 0.f, 0.f};
    }
    // cvt + LDS stage: granule h8 = q*32 + lane/2, half = lane&1
#pragma unroll
    for (int q = 0; q < 4; q++) {
        union { ushort2 u2[2]; uint2 u; } t;
        t.u2[0] = f2bf2(v[q].x, v[q].y);
        t.u2[1] = f2bf2(v[q].z, v[q].w);
        *(uint2*)&rb[wv][q * 32 + (lane >> 1)][(lane & 1) * 4] = t.u;
    }
    // cluster logits (wave-uniform branch; register-only reduce)
    if (slot < Mk) {
        float acc[KCL];
#pragma unroll
        for (int kk = 0; kk < KCL; kk++) acc[kk] = 0.f;
#pragma unroll
        for (int q = 0; q < 4; q++) {
            const float* vf = (const float*)&v[q];
#pragma unroll
            for (int e = 0; e < 4; e++) {
                const int h = q * 256 + lane * 4 + e;
                const float xv = vf[e];
                const float4* cwr = (const float4*)(cw + (size_t)h * KCL);
#pragma unroll
                for (int qq = 0; qq < 4; qq++) {
                    float4 wgt = cwr[qq];
                    acc[qq * 4 + 0] += xv * wgt.x;
                    acc[qq * 4 + 1] += xv * wgt.y;
                    acc[qq * 4 + 2] += xv * wgt.z;
                    acc[qq * 4 + 3] += xv * wgt.w;
                }
            }
        }
#pragma unroll
        for (int off = 32; off >= 1; off >>= 1) {
#pragma unroll
            for (int kk = 0; kk < KCL; kk++) acc[kk] += __shfl_down(acc[kk], off);
        }
        if (lane == 0) {
            const int n = ws_i[WS_ROWS + k * NROW + slot];
            float m = acc[0];
#pragma unroll
            for (int kk = 1; kk < KCL; kk++) m = fmaxf(m, acc[kk]);
            float s = 0.f;
#pragma unroll
            for (int kk = 0; kk < KCL; kk++) s += __expf(acc[kk] - m);
            ws_f[WS_PART + n] = (m + __logf(s)) - acc[k];
        }
    }
    __syncthreads();
    // write out: thread -> (h8 = tid>>1, slots sp..sp+1), 32B contiguous
    {
        const int h8 = threadIdx.x >> 1;
        const int sp = (threadIdx.x & 1) * 2;
        short* o = (short*)(ws_i + WS_XG)
                 + ((size_t)k * (128 * 256) + (size_t)h8 * 256 + slot0 + sp) * 8;
        *(short8*)(o)     = *(const short8*)&rb[sp][h8][0];
        *(short8*)(o + 8) = *(const short8*)&rb[sp + 1][h8][0];
    }
}

// ---------------------------------------------------------------------------
// Kernel 3: tail GEMM, barrier-free K-loop, CONCURRENCY-MAXIMIZED.
// Tile 192 rows x 32 cols; 4 waves (2 row-halves x 2 col-halves), each wave
// 96r x 16c -> acc[6][1] keeps VGPR ~120 -> 4 waves/SIMD (16 waves/CU).
// Grid 99x16 = 1584 working blocks (~6.2/CU). Per wave ~14 loads outstanding
// (2-buffer unrolled pipeline) -> per-CU in-flight ~16-25 KB > 9.2 KB BDP.
// XCD-swizzle: same-cluster blocks -> same XCD so the A panel (0.5 MB)
// stays L2-resident across its 99 col-tile readers.
// ---------------------------------------------------------------------------
__launch_bounds__(256, 4)
__global__ void tail_kernel(const float* __restrict__ logits,
                            const int* ws_i, float* ws_f) {
    __shared__ int   lrow[MT];
    __shared__ int   ltcol[MT];
    __shared__ float rowsum[MT];

    // XCD-aware remap of (x,y): id%16 -> cluster (interleaved so the 8 XCDs
    // each own 2 clusters), id/16 -> col tile. Bijective over 99*16.
    const int id = blockIdx.x + NCT * blockIdx.y;
    const int k  = (id & 7) * 2 + ((id >> 3) & 1);
    const int ct = id >> 4;
    const int rt = blockIdx.z;
    int Mk = ws_i[WS_COUNTS + k];
    if (Mk > CAP) Mk = CAP;
    if (rt * MT >= Mk) return;   // z=1 only fires if Mk>192 (~6 sigma)

    const int tid = threadIdx.x;
    if (tid < MT) {
        int r = rt * MT + tid;
        int rid = (r < Mk) ? ws_i[WS_ROWS + k * NROW + r] : -1;
        lrow[tid]  = rid;
        ltcol[tid] = (rid >= 0) ? ws_i[WS_TCOL + rid] : -1;
        rowsum[tid] = 0.f;
    }
    __syncthreads();

    const int w = tid >> 6, l = tid & 63;
    const int wr = (w & 1) * 96;        // wave row-half (96 rows)
    const int wc = (w >> 1) * 16;       // wave col-half (16 cols)
    const int quad = l >> 4, lm = l & 15;

    // A: xgT granule (h8 = t*4 + quad, slot = rt*MT + wr + mi*16 + lm)
    const short* xgT = (const short*)(ws_i + WS_XG);
    const short* aBase = xgT
        + (((size_t)k * 128 + quad) * 256 + (size_t)(rt * MT + wr + lm)) * 8;

    // B: lane owns col ct*32 + wc + lm (clamped; masked in epilogue),
    // k-rows quad*8 + j per step.
    int c0 = ct * NTC + wc + lm;
    if (c0 >= CDIM) c0 = CDIM - 1;
    const float* bBase = logits + (size_t)(quad * 8) * VOC + (size_t)k * CDIM + c0;

    f32x4 acc[6];
#pragma unroll
    for (int mi = 0; mi < 6; mi++) acc[mi] = (f32x4)(0.f);

    float  bv0[8], bv1[8];
    short8 af0[6], af1[6];

    auto LOADB = [&](int t, float* bv) {
        const float* p = bBase + (size_t)(t * 32) * VOC;
#pragma unroll
        for (int j = 0; j < 8; j++) bv[j] = p[(size_t)j * VOC];
    };
    auto LOADA = [&](int t, short8* af) {
        const short* p = aBase + (size_t)t * 8192;   // 4 h8-granules * 256 * 8
#pragma unroll
        for (int mi = 0; mi < 6; mi++)
            af[mi] = *(const short8*)(p + mi * 128); // mi*16 slots * 8
    };
    auto COMPUTE = [&](float* bv, short8* af) {
        union { ushort2 u2[4]; short8 s8; } u;
#pragma unroll
        for (int jj = 0; jj < 4; jj++) u.u2[jj] = f2bf2(bv[2 * jj], bv[2 * jj + 1]);
#pragma unroll
        for (int mi = 0; mi < 6; mi++)
            acc[mi] = __builtin_amdgcn_mfma_f32_16x16x32_bf16(
                af[mi], u.s8, acc[mi], 0, 0, 0);
    };

    // ---- software-pipelined K-loop (no barriers, counted vmcnt waits) ----
    LOADB(0, bv0); LOADA(0, af0);
    LOADB(1, bv1); LOADA(1, af1);
    for (int t = 0; t < HDIM / 32; t += 2) {
        COMPUTE(bv0, af0);
        if (t + 2 < HDIM / 32) { LOADB(t + 2, bv0); LOADA(t + 2, af0); }
        COMPUTE(bv1, af1);
        if (t + 3 < HDIM / 32) { LOADB(t + 3, bv1); LOADA(t + 3, af1); }
    }

    // ---- epilogue: per-row sum(exp) + target logit ----
    // C/D layout: col = lane&15, row = (lane>>4)*4 + reg  [m89-verified]
    const int cl = ct * NTC + wc + lm;
#pragma unroll
    for (int mi = 0; mi < 6; mi++) {
#pragma unroll
        for (int r = 0; r < 4; r++) {
            int row_local = wr + mi * 16 + quad * 4 + r;
            int rid = lrow[row_local];
            int tc  = ltcol[row_local];
            float z = acc[mi][r];
            float s = 0.f;
            if (rid >= 0 && cl < CDIM) {
                s = __expf(z);
                if (cl == tc) ws_f[WS_ZTGT + rid] = z;
            }
            s += __shfl_xor(s, 1);
            s += __shfl_xor(s, 2);
            s += __shfl_xor(s, 4);
            s += __shfl_xor(s, 8);
            if (lm == 0 && rid >= 0) atomicAdd(&rowsum[row_local], s);
        }
    }
    __syncthreads();
    if (tid < MT) {
        int rid = lrow[tid];
        if (rid >= 0) atomicAdd(&ws_f[WS_SUMEXP + rid], rowsum[tid]);
    }
}

// ---------------------------------------------------------------------------
// Kernel 4: nll[n] = part[n] + log(sum_exp_tail[n]) - z_target[n]
// ---------------------------------------------------------------------------
__global__ void finalize_kernel(const float* ws_f, float* __restrict__ out) {
    int n = blockIdx.x * 256 + threadIdx.x;
    if (n >= NROW) return;
    out[n] = ws_f[WS_PART + n] + __logf(ws_f[WS_SUMEXP + n]) - ws_f[WS_ZTGT + n];
}

// ---------------------------------------------------------------------------
extern "C" void kernel_launch(void* const* d_in, const int* in_sizes, int n_in,
                              void* d_out, int out_size, void* d_ws, size_t ws_size,
                              hipStream_t stream) {
    const float* x      = (const float*)d_in[0];
    const int*   y      = (const int*)d_in[1];
    const int*   y_pos  = (const int*)d_in[2];
    // d_in[3] (pos2token) is the identity partition by construction; unused.
    const int*   tip    = (const int*)d_in[4];
    const float* cw     = (const float*)d_in[5];
    const float* logits = (const float*)d_in[6];
    float* out  = (float*)d_out;
    float* ws_f = (float*)d_ws;
    int*   ws_i = (int*)d_ws;

    // zero sumexp[2048] + counts[16] (contiguous at ws start)
    hipMemsetAsync(d_ws, 0, (size_t)(NROW + KCL) * 4, stream);

    scatter_kernel<<<NROW / 256, 256, 0, stream>>>(y, y_pos, tip, ws_i);
    // 16 clusters x 64 blocks (4 slots each): gather+transpose+cluster lse
    prep_kernel<<<KCL * CAP / 4, 256, 0, stream>>>(x, cw, ws_i, ws_f);

    // 99 col tiles x 16 clusters (x2 row guard) -> 1584 working blocks,
    // B read from HBM exactly once.
    dim3 grid(NCT, KCL, 2);
    tail_kernel<<<grid, 256, 0, stream>>>(logits, ws_i, ws_f);

    finalize_kernel<<<NROW / 256, 256, 0, stream>>>(ws_f, out);
}